// Round 7
// baseline (144.642 us; speedup 1.0000x reference)
//
#include <hip/hip_runtime.h>
#include <stdint.h>
#include <float.h>

#define BLK 256
#define IPT 16                // owner points per thread (16 independent min-chains)
#define OWNERS (BLK * IPT)    // 4096 owners per block
#define SLICE 128             // scanned points per block (2 KB LDS)

typedef unsigned long long ull;

// Monotone float -> uint transform (preserves <, total order) and inverse.
__device__ __forceinline__ unsigned int ford(float f) {
    int b = __float_as_int(f);
    return (b >= 0) ? ((unsigned)b ^ 0x80000000u) : ~(unsigned)b;
}
__device__ __forceinline__ float ford_inv(unsigned int u) {
    int b = (u & 0x80000000u) ? (int)(u ^ 0x80000000u) : (int)~u;
    return __int_as_float(b);
}

// Phase 1: min VALUE only, pure 4 VALU/pair (3 fma + 1 min), NO index or
// subtile tracking in the hot loop. Result = (ford(best)<<32 | slice_base):
// u64-min gives min value, ties -> smallest slice_base (= earliest slice =
// numpy first occurrence after in-slice recovery). Stored complemented via
// atomicMax so all-zero workspace init is "empty" (single memset covers mins
// + accumulator + done counter).
// IPT=16: LDS pipe demand = 4 SIMD / (16*4 inst * 2 cyc) = 1 read / 32 cyc
// vs ds_read_b128 supply 1/12 cyc -> 37% LDS load (was 75% at IPT=8).
__global__ __launch_bounds__(BLK, 4) void nn_min_dual(
    const float* __restrict__ p, const float* __restrict__ g,
    ull* __restrict__ rowmin, ull* __restrict__ colmin,
    int rowBlocks, int rowSlices, int colSlices)
{
    __shared__ float4 sb[SLICE];

    const float* A; const float* B; ull* outmin; int id, nSlices;
    if ((int)blockIdx.x < rowBlocks) {
        id = blockIdx.x;             A = p; B = g; outmin = rowmin; nSlices = rowSlices;
    } else {
        id = blockIdx.x - rowBlocks; A = g; B = p; outmin = colmin; nSlices = colSlices;
    }
    const int chunk = id / nSlices;
    const int slice = id - chunk * nSlices;
    const int s0 = slice * SLICE;

    // Stage slice (coords + |B|^2). Explicit fmaf chain: finalize recomputes
    // the identical expression so bit-exact equality holds.
    if (threadIdx.x < SLICE) {
        int s = s0 + threadIdx.x;
        float bx = B[3 * s], by = B[3 * s + 1], bz = B[3 * s + 2];
        float w = fmaf(bz, bz, fmaf(by, by, bx * bx));
        sb[threadIdx.x] = make_float4(bx, by, bz, w);
    }

    const int o0 = chunk * OWNERS + threadIdx.x;
    float ax[IPT], ay[IPT], az[IPT], best[IPT];
#pragma unroll
    for (int r = 0; r < IPT; ++r) {
        int o = o0 + r * BLK;
        ax[r] = -2.0f * A[3 * o];
        ay[r] = -2.0f * A[3 * o + 1];
        az[r] = -2.0f * A[3 * o + 2];
        best[r] = FLT_MAX;
    }
    __syncthreads();

#pragma unroll 4
    for (int k = 0; k < SLICE; ++k) {
        float4 q = sb[k];    // wave-uniform broadcast read, conflict-free
#pragma unroll
        for (int r = 0; r < IPT; ++r) {
            float v = fmaf(ax[r], q.x, fmaf(ay[r], q.y, fmaf(az[r], q.z, q.w)));
            best[r] = fminf(best[r], v);
        }
    }

#pragma unroll
    for (int r = 0; r < IPT; ++r) {
        ull packed = ((ull)ford(best[r]) << 32) | (unsigned)s0;
        atomicMax(&outmin[o0 + r * BLK], ~packed);
    }
}

// Phase 2 + finalize, one WAVE per owner, 8 owners/wave (independent ->
// loads pipeline): 64 lanes re-evaluate the winning 128-pt slice (2 rounds)
// with the bit-identical fma chain, coalesced loads; ballot+ffs gives the
// first exact match (numpy tie-break). Lane 0 gathers the normal and
// accumulates (1-dot)*inv. Block partials -> accumulator; last finishing
// block writes d_out (no d_out memset node).
__global__ __launch_bounds__(BLK) void finalize_kernel(
    const ull* __restrict__ rowmin, const ull* __restrict__ colmin,
    const float* __restrict__ p, const float* __restrict__ g,
    const float* __restrict__ pn, const float* __restrict__ gn,
    float* __restrict__ out, float* __restrict__ accum,
    unsigned int* __restrict__ done,
    int N, int M, float invN, float invM)
{
    const int lane = threadIdx.x & 63;
    const int wid  = (blockIdx.x * BLK + threadIdx.x) >> 6;
    const int nw   = (gridDim.x * BLK) >> 6;

    float wsum = 0.0f;
    for (int o = wid; o < N + M; o += nw) {
        const float* A; const float* B; const float* An; const float* Bn;
        ull stored; int oo; float inv;
        if (o < N) { oo = o;     A = p; B = g; An = pn; Bn = gn; stored = rowmin[oo]; inv = invN; }
        else       { oo = o - N; A = g; B = p; An = gn; Bn = pn; stored = colmin[oo]; inv = invM; }
        ull packed = ~stored;
        float bestv = ford_inv((unsigned int)(packed >> 32));
        int base = (int)(packed & 0xffffffffull);

        float ax = -2.0f * A[3 * oo];
        float ay = -2.0f * A[3 * oo + 1];
        float az = -2.0f * A[3 * oo + 2];

        int s1 = base + lane;                      // coalesced 64-pt round 1
        float bx1 = B[3 * s1], by1 = B[3 * s1 + 1], bz1 = B[3 * s1 + 2];
        int s2 = s1 + 64;                          // coalesced 64-pt round 2
        float bx2 = B[3 * s2], by2 = B[3 * s2 + 1], bz2 = B[3 * s2 + 2];

        float w1 = fmaf(bz1, bz1, fmaf(by1, by1, bx1 * bx1));
        float v1 = fmaf(ax, bx1, fmaf(ay, by1, fmaf(az, bz1, w1)));
        float w2 = fmaf(bz2, bz2, fmaf(by2, by2, bx2 * bx2));
        float v2 = fmaf(ax, bx2, fmaf(ay, by2, fmaf(az, bz2, w2)));

        ull m1 = __ballot(v1 == bestv);
        ull m2 = __ballot(v2 == bestv);
        int j = m1 ? (base + __ffsll(m1) - 1)
                   : (m2 ? (base + 64 + __ffsll(m2) - 1) : base);

        if (lane == 0) {
            float d = An[3 * oo] * Bn[3 * j] + An[3 * oo + 1] * Bn[3 * j + 1]
                    + An[3 * oo + 2] * Bn[3 * j + 2];
            wsum += (1.0f - d) * inv;
        }
    }

    __shared__ float part[BLK / 64];
    if (lane == 0) part[threadIdx.x >> 6] = wsum;
    __syncthreads();
    if (threadIdx.x == 0) {
        float s = 0.0f;
#pragma unroll
        for (int w = 0; w < BLK / 64; ++w) s += part[w];
        atomicAdd(accum, s);
        __threadfence();
        unsigned int c = atomicAdd(done, 1u);
        if (c == gridDim.x - 1) {
            __threadfence();
            float tot = atomicAdd(accum, 0.0f);    // atomic read of final sum
            out[0] = tot;
        }
    }
}

extern "C" void kernel_launch(void* const* d_in, const int* in_sizes, int n_in,
                              void* d_out, int out_size, void* d_ws, size_t ws_size,
                              hipStream_t stream) {
    const float* p  = (const float*)d_in[0];   // [N,3] predicted points
    const float* pn = (const float*)d_in[1];   // [N,3] predicted normals (unit)
    const float* g  = (const float*)d_in[2];   // [M,3] gt points
    const float* gn = (const float*)d_in[3];   // [M,3] gt normals (unit)
    const int N = in_sizes[0] / 3;             // 8192
    const int M = in_sizes[2] / 3;             // 32768

    ull* rowmin = (ull*)d_ws;                  // [N]   (stored complemented)
    ull* colmin = rowmin + N;                  // [M]   (stored complemented)
    float* accum = (float*)(colmin + M);       // scalar accumulator
    unsigned int* done = (unsigned int*)(accum + 1);
    float* out = (float*)d_out;

    // Single zero-memset: mins (0 == "empty" for complemented atomicMax),
    // float accumulator, done counter.
    hipMemsetAsync(d_ws, 0, (size_t)(N + M) * sizeof(ull) + 16, stream);

    const int rowSlices = M / SLICE;                 // 256
    const int colSlices = N / SLICE;                 // 64
    const int rowBlocks = (N / OWNERS) * rowSlices;  // 2*256 = 512
    const int colBlocks = (M / OWNERS) * colSlices;  // 8*64  = 512
    nn_min_dual<<<rowBlocks + colBlocks, BLK, 0, stream>>>(
        p, g, rowmin, colmin, rowBlocks, rowSlices, colSlices);

    finalize_kernel<<<1280, BLK, 0, stream>>>(
        rowmin, colmin, p, g, pn, gn, out, accum, done, N, M, 1.0f / N, 1.0f / M);
}

// Round 8
// 144.322 us; speedup vs baseline: 1.0022x; 1.0022x over previous
//
#include <hip/hip_runtime.h>
#include <stdint.h>
#include <float.h>

#define BLK 256
#define IPT 8                 // owner points per thread (8 independent min-chains)
#define OWNERS (BLK * IPT)    // 2048 owners per block
#define SLICE 128             // scanned points per block (2 KB LDS)
#define SUB 64                // subtile granularity for deferred-index recovery

typedef unsigned long long ull;

// Monotone float -> uint transform (preserves <, total order) and inverse.
__device__ __forceinline__ unsigned int ford(float f) {
    int b = __float_as_int(f);
    return (b >= 0) ? ((unsigned)b ^ 0x80000000u) : ~(unsigned)b;
}
__device__ __forceinline__ float ford_inv(unsigned int u) {
    int b = (u & 0x80000000u) ? (int)(u ^ 0x80000000u) : (int)~u;
    return __int_as_float(b);
}

// Phase 1 (R4-proven fastest variant, ~47us = ~89% of the measured-practical
// fp32 VALU ceiling): min VALUE only (3 fma + 1 min per pair). Per 64-point
// subtile, record the subtile base if the running min improved (strict <:
// first-improving subtile wins, matching numpy ties). Merge via u64 atomicMin
// of (ford(best)<<32 | subtile_base): equal values resolve to the smallest
// base = first occurrence. Exact index recovered in finalize by re-scanning
// the 64-pt subtile with a bit-identical fma chain.
__global__ __launch_bounds__(BLK) void nn_min_dual(
    const float* __restrict__ p, const float* __restrict__ g,
    ull* __restrict__ rowmin, ull* __restrict__ colmin,
    int rowBlocks, int rowSlices, int colSlices)
{
    __shared__ float4 sb[SLICE];

    const float* A; const float* B; ull* outmin; int id, nSlices;
    if ((int)blockIdx.x < rowBlocks) {
        id = blockIdx.x;             A = p; B = g; outmin = rowmin; nSlices = rowSlices;
    } else {
        id = blockIdx.x - rowBlocks; A = g; B = p; outmin = colmin; nSlices = colSlices;
    }
    const int chunk = id / nSlices;
    const int slice = id - chunk * nSlices;
    const int s0 = slice * SLICE;

    // Stage slice (coords + |B|^2). Explicit fmaf chain: finalize recomputes
    // the identical expression so bit-exact equality holds.
    if (threadIdx.x < SLICE) {
        int s = s0 + threadIdx.x;
        float bx = B[3 * s], by = B[3 * s + 1], bz = B[3 * s + 2];
        float w = fmaf(bz, bz, fmaf(by, by, bx * bx));
        sb[threadIdx.x] = make_float4(bx, by, bz, w);
    }

    const int o0 = chunk * OWNERS + threadIdx.x;
    float ax[IPT], ay[IPT], az[IPT], best[IPT];
    int base[IPT];
#pragma unroll
    for (int r = 0; r < IPT; ++r) {
        int o = o0 + r * BLK;
        ax[r] = -2.0f * A[3 * o];
        ay[r] = -2.0f * A[3 * o + 1];
        az[r] = -2.0f * A[3 * o + 2];
        best[r] = FLT_MAX;
        base[r] = s0;
    }
    __syncthreads();

    for (int st = 0; st < SLICE; st += SUB) {
        float prev[IPT];
#pragma unroll
        for (int r = 0; r < IPT; ++r) prev[r] = best[r];
#pragma unroll 4
        for (int k = st; k < st + SUB; ++k) {
            float4 q = sb[k];    // wave-uniform broadcast read, conflict-free
#pragma unroll
            for (int r = 0; r < IPT; ++r) {
                float v = fmaf(ax[r], q.x, fmaf(ay[r], q.y, fmaf(az[r], q.z, q.w)));
                best[r] = fminf(best[r], v);
            }
        }
#pragma unroll
        for (int r = 0; r < IPT; ++r)
            if (best[r] < prev[r]) base[r] = s0 + st;   // strict <: first subtile wins
    }

#pragma unroll
    for (int r = 0; r < IPT; ++r) {
        ull packed = ((ull)ford(best[r]) << 32) | (unsigned)base[r];
        atomicMin(&outmin[o0 + r * BLK], packed);
    }
}

// Phase 2 + finalize, one WAVE per owner (coalesced recovery), NO fences:
// 64 lanes re-evaluate the winning 64-pt subtile with the bit-identical fma
// chain; ballot+ffs picks the first exact match (numpy tie-break). Lane 0
// gathers the normal and accumulates (1-dot)*inv. One plain atomicAdd per
// block into memset-zeroed d_out. (R6/R7's __threadfence pair per block
// forced per-block XCD-L2 writebacks -> tens of us; removed.)
__global__ __launch_bounds__(BLK) void finalize_kernel(
    const ull* __restrict__ rowmin, const ull* __restrict__ colmin,
    const float* __restrict__ p, const float* __restrict__ g,
    const float* __restrict__ pn, const float* __restrict__ gn,
    float* __restrict__ out, int N, int M, float invN, float invM)
{
    const int lane = threadIdx.x & 63;
    const int wid  = (blockIdx.x * BLK + threadIdx.x) >> 6;
    const int nw   = (gridDim.x * BLK) >> 6;

    float wsum = 0.0f;
    for (int o = wid; o < N + M; o += nw) {
        const float* A; const float* B; const float* An; const float* Bn;
        ull packed; int oo; float inv;
        if (o < N) { oo = o;     A = p; B = g; An = pn; Bn = gn; packed = rowmin[oo]; inv = invN; }
        else       { oo = o - N; A = g; B = p; An = gn; Bn = pn; packed = colmin[oo]; inv = invM; }
        float bestv = ford_inv((unsigned int)(packed >> 32));
        int base = (int)(packed & 0xffffffffull);

        float ax = -2.0f * A[3 * oo];
        float ay = -2.0f * A[3 * oo + 1];
        float az = -2.0f * A[3 * oo + 2];

        int s = base + lane;                       // coalesced: 64 consecutive points
        float bx = B[3 * s], by = B[3 * s + 1], bz = B[3 * s + 2];
        float w = fmaf(bz, bz, fmaf(by, by, bx * bx));
        float v = fmaf(ax, bx, fmaf(ay, by, fmaf(az, bz, w)));

        ull mask = __ballot(v == bestv);           // bit-exact recompute: non-empty
        int bit = mask ? (__ffsll(mask) - 1) : 0;  // first (smallest s) match
        int j = base + bit;

        if (lane == 0) {
            float d = An[3 * oo] * Bn[3 * j] + An[3 * oo + 1] * Bn[3 * j + 1]
                    + An[3 * oo + 2] * Bn[3 * j + 2];
            wsum += (1.0f - d) * inv;
        }
    }

    __shared__ float part[BLK / 64];
    if (lane == 0) part[threadIdx.x >> 6] = wsum;
    __syncthreads();
    if (threadIdx.x == 0) {
        float s = 0.0f;
#pragma unroll
        for (int w = 0; w < BLK / 64; ++w) s += part[w];
        atomicAdd(out, s);
    }
}

extern "C" void kernel_launch(void* const* d_in, const int* in_sizes, int n_in,
                              void* d_out, int out_size, void* d_ws, size_t ws_size,
                              hipStream_t stream) {
    const float* p  = (const float*)d_in[0];   // [N,3] predicted points
    const float* pn = (const float*)d_in[1];   // [N,3] predicted normals (unit)
    const float* g  = (const float*)d_in[2];   // [M,3] gt points
    const float* gn = (const float*)d_in[3];   // [M,3] gt normals (unit)
    const int N = in_sizes[0] / 3;             // 8192
    const int M = in_sizes[2] / 3;             // 32768

    ull* rowmin = (ull*)d_ws;                  // [N]
    ull* colmin = rowmin + N;                  // [M]
    float* out = (float*)d_out;

    hipMemsetAsync(d_ws, 0xFF, (size_t)(N + M) * sizeof(ull), stream);
    hipMemsetAsync(d_out, 0, sizeof(float), stream);

    const int rowSlices = M / SLICE;                 // 256
    const int colSlices = N / SLICE;                 // 64
    const int rowBlocks = (N / OWNERS) * rowSlices;  // 4*256 = 1024
    const int colBlocks = (M / OWNERS) * colSlices;  // 16*64 = 1024
    nn_min_dual<<<rowBlocks + colBlocks, BLK, 0, stream>>>(
        p, g, rowmin, colmin, rowBlocks, rowSlices, colSlices);

    // 2560 blocks -> 10240 waves -> 4 independent owners per wave (pipelined).
    finalize_kernel<<<2560, BLK, 0, stream>>>(
        rowmin, colmin, p, g, pn, gn, out, N, M, 1.0f / N, 1.0f / M);
}